// Round 1
// 342.190 us; speedup vs baseline: 1.0045x; 1.0045x over previous
//
#include <hip/hip_runtime.h>
#include <math.h>

// EdgeFeaturizer: per-row top-12 smallest of 8192x8192 fp32 + 50-bin RBF.
// d_out (float32): [8192*12*2] edge_index encoded as floats, then
// [8192*12*50] features.
//
// R5: NON-TEMPORAL streaming loads (carried). The harness re-poisons d_ws
// (1 GiB) to 0xAA before every timed replay; nt loads don't allocate in
// L2/L3 -> no forced writeback drain of the dirty poison data.
//
// R6: OCCUPANCY + simplified compaction. Rank-select is order-independent
// (rank = #keys strictly smaller; keys unique), so the ordered per-lane
// LDS buckets (24 KiB) + shfl-prefix compaction were pure overhead.
// Replace with unordered LDS atomicAdd append into s_keys (~82 atomics
// per row, negligible). LDS/block 30.8 KiB -> ~6.6 KiB and
// __launch_bounds__(256,8) caps VGPR at 64 -> target 32 waves/CU (whole
// grid resident) for maximal independent HBM streams during the
// poison-contended window.
// Key=(float_bits<<32)|idx == top_k's (dist asc, idx asc) order.
// Exact per-wave fallback guarantees correctness for any input.

#define N_ATOMS 8192
#define K 12
#define NBINS 50
#define CAP 192          // total candidates/row: Binom(8192,0.01) mean 82
#define WAVES 4
#define BLOCK (WAVES * 64)
#define MAX_RADIUS 8.0f
#define CAND_T 0.01f

typedef float f4 __attribute__((ext_vector_type(4)));

__global__ __launch_bounds__(BLOCK, 8) void edge_kernel(const float* __restrict__ dm,
                                                        float* __restrict__ out) {
    const int wave = threadIdx.x >> 6;
    const int lane = threadIdx.x & 63;
    const int row = blockIdx.x * WAVES + wave;
    const float* rowp = dm + (size_t)row * N_ATOMS;
    const f4* row4 = (const f4*)rowp;

    __shared__ unsigned long long s_keys[WAVES][CAP];  // 6 KiB
    __shared__ int s_cnt[WAVES];
    __shared__ int s_selidx[WAVES][K];
    __shared__ float s_seldist[WAVES][K];

    // Same-wave DS ops complete in order: lane0's init is visible to this
    // wave's later atomics without a block barrier.
    if (lane == 0) s_cnt[wave] = 0;

    // ---- phase 1: non-temporal streaming scan, unordered LDS append ----
    #pragma unroll
    for (int i = 0; i < 8; ++i) {
        f4 v[4];
        #pragma unroll
        for (int j = 0; j < 4; ++j)
            v[j] = __builtin_nontemporal_load(&row4[lane + (i * 4 + j) * 64]);
        #pragma unroll
        for (int j = 0; j < 4; ++j) {
            int bidx = (lane + (i * 4 + j) * 64) * 4;
            #pragma unroll
            for (int c = 0; c < 4; ++c) {
                float d = v[j][c];
                if (d < CAND_T) {
                    int pos = atomicAdd(&s_cnt[wave], 1);
                    if (pos < CAP)
                        s_keys[wave][pos] =
                            ((unsigned long long)__float_as_uint(d) << 32) |
                            (unsigned int)(bidx + c);
                }
            }
        }
    }
    __syncthreads();  // LDS write->read visibility (and keeps waves phased)

    const int total = s_cnt[wave];

    if (total >= K && total <= CAP) {
        // ---- rank select: rank = #keys strictly smaller (keys unique) ----
        for (int j = lane; j < total; j += 64) {
            unsigned long long kj = s_keys[wave][j];
            int rank = 0;
            for (int m2 = 0; m2 < total; ++m2)       // broadcast reads
                rank += (s_keys[wave][m2] < kj) ? 1 : 0;
            if (rank < K) {
                s_selidx[wave][rank] = (int)(kj & 0xFFFFFFFFull);
                s_seldist[wave][rank] =
                    __uint_as_float((unsigned int)(kj >> 32));
            }
        }
    } else {
        // ---- exact per-wave fallback (never taken on this input) ----
        unsigned long long last = 0ull;
        for (int r = 0; r < K; ++r) {
            unsigned long long best = ~0ull;
            for (int i = 0; i < 32; ++i) {
                int v4 = lane + i * 64;
                f4 v = __builtin_nontemporal_load(&row4[v4]);
                int bidx = v4 * 4;
                #pragma unroll
                for (int c = 0; c < 4; ++c) {
                    float d = v[c];
                    float md = (d <= MAX_RADIUS) ? d
                                                 : __uint_as_float(0x7F800000u);
                    unsigned long long key =
                        ((unsigned long long)__float_as_uint(md) << 32) |
                        (unsigned int)(bidx + c);
                    if (((r == 0) || (key > last)) && key < best) best = key;
                }
            }
            #pragma unroll
            for (int off = 32; off > 0; off >>= 1) {
                unsigned long long other = __shfl_xor(best, off, 64);
                if (other < best) best = other;
            }
            if (lane == 0) {
                int idx = (int)(best & 0xFFFFFFFFull);
                s_selidx[wave][r] = idx;
                s_seldist[wave][r] = rowp[idx];  // original dm value
            }
            last = best;
        }
    }

    // ---- outputs (non-temporal: never re-read). Same-wave DS ordering
    // makes selidx/seldist visible without another barrier. ----
    float* out_ei = out;
    float* out_ef = out + (size_t)N_ATOMS * K * 2;
    if (lane < 2 * K) {
        int r = lane >> 1, comp = lane & 1;
        __builtin_nontemporal_store(
            comp ? (float)s_selidx[wave][r] : (float)row,
            &out_ei[((size_t)row * K + r) * 2 + comp]);
    }
    for (int t = lane; t < K * NBINS; t += 64) {
        int r = t / NBINS, b = t - r * NBINS;
        float d = s_seldist[wave][r];
        float z = (d - (float)b * (1.0f / 49.0f)) * 5.0f;
        __builtin_nontemporal_store(__expf(-0.5f * z * z),
                                    &out_ef[(size_t)row * K * NBINS + t]);
    }
}

extern "C" void kernel_launch(void* const* d_in, const int* in_sizes, int n_in,
                              void* d_out, int out_size, void* d_ws, size_t ws_size,
                              hipStream_t stream) {
    const float* dm = (const float*)d_in[0];
    float* out = (float*)d_out;
    edge_kernel<<<N_ATOMS / WAVES, BLOCK, 0, stream>>>(dm, out);
}